// Round 1
// baseline (1168.484 us; speedup 1.0000x reference)
//
#include <hip/hip_runtime.h>
#include <cstddef>

#define NNODE 10000
#define IND 512
#define HD 256

// ---------------------------------------------------------------------------
// 1. count degrees (src side for dinv, dst side for CSR rows)
// ---------------------------------------------------------------------------
__global__ void count_kernel(const int* __restrict__ src, const int* __restrict__ dst,
                             int E, int* __restrict__ cnt_src, int* __restrict__ cnt_dst) {
    int e = blockIdx.x * blockDim.x + threadIdx.x;
    if (e < E) {
        atomicAdd(&cnt_src[src[e]], 1);
        atomicAdd(&cnt_dst[dst[e]], 1);
    }
}

// ---------------------------------------------------------------------------
// 2. dinv + exclusive scan of cnt_dst -> row_ptr (single block, 1024 threads)
// ---------------------------------------------------------------------------
__global__ __launch_bounds__(1024) void scan_kernel(const int* __restrict__ cnt_src,
                                                    const int* __restrict__ cnt_dst,
                                                    float* __restrict__ dinv,
                                                    int* __restrict__ row_ptr) {
    int t = threadIdx.x;
    for (int i = t; i < NNODE; i += 1024)
        dinv[i] = rsqrtf(fmaxf((float)cnt_src[i], 1.0f));

    __shared__ int sums[1024];
    const int CH = (NNODE + 1023) / 1024;  // 10
    int base = t * CH;
    int s = 0;
    for (int i = 0; i < CH; ++i) {
        int idx = base + i;
        if (idx < NNODE) s += cnt_dst[idx];
    }
    sums[t] = s;
    __syncthreads();
    for (int off = 1; off < 1024; off <<= 1) {
        int v = (t >= off) ? sums[t - off] : 0;
        __syncthreads();
        sums[t] += v;
        __syncthreads();
    }
    int run = (t == 0) ? 0 : sums[t - 1];
    for (int i = 0; i < CH; ++i) {
        int idx = base + i;
        if (idx < NNODE) { row_ptr[idx] = run; run += cnt_dst[idx]; }
    }
    if (t == 1023) row_ptr[NNODE] = sums[1023];
}

// ---------------------------------------------------------------------------
// 3. fill CSR (by dst): col[] holds src of each edge
// ---------------------------------------------------------------------------
__global__ void fill_kernel(const int* __restrict__ src, const int* __restrict__ dst,
                            int E, const int* __restrict__ row_ptr,
                            int* __restrict__ cursor, int* __restrict__ col) {
    int e = blockIdx.x * blockDim.x + threadIdx.x;
    if (e < E) {
        int v = dst[e];
        int pos = row_ptr[v] + atomicAdd(&cursor[v], 1);
        col[pos] = src[e];
    }
}

// ---------------------------------------------------------------------------
// 4. combine weights w_k = sum_i c_i * THETA[i][k], c = sigmoids of lam
//    THETA rows (ascending powers), D=4:
//    i=0: (1-x/2)^4/0.2, i=1: (x/2)(1-x/2)^3/0.05, i=2: (x/2)^2(1-x/2)^2*30,
//    i=3: (x/2)^3(1-x/2)/0.05, i=4: (x/2)^4/0.2
// ---------------------------------------------------------------------------
__global__ void w_kernel(const float* __restrict__ lam, float* __restrict__ w) {
    if (threadIdx.x == 0 && blockIdx.x == 0) {
        float c[5];
        float s0 = 1.0f / (1.0f + expf(-lam[0]));
        c[0] = s0;
        c[1] = s0;  // reference reuses lam[0] for all_h[1]
        c[2] = 1.0f / (1.0f + expf(-lam[1]));
        c[3] = 1.0f / (1.0f + expf(-lam[2]));
        c[4] = 1.0f / (1.0f + expf(-lam[3]));
        const float TH[5][5] = {
            {5.0f, -10.0f,  7.5f, -2.5f, 0.3125f},
            {0.0f,  10.0f, -15.0f, 7.5f, -1.25f },
            {0.0f,   0.0f,  7.5f, -7.5f, 1.875f },
            {0.0f,   0.0f,  0.0f,  2.5f, -1.25f },
            {0.0f,   0.0f,  0.0f,  0.0f, 0.3125f}};
        for (int k = 0; k < 5; ++k) {
            float acc = 0.0f;
            for (int i = 0; i < 5; ++i) acc += c[i] * TH[i][k];
            w[k] = acc;
        }
    }
}

// ---------------------------------------------------------------------------
// 5. GEMM1: h = leaky_relu(in_feat @ W + b); f_a = h; recons = w0 * h
//    64x64 tile, 256 threads, 4x4 per thread, K-step 16
// ---------------------------------------------------------------------------
__global__ __launch_bounds__(256) void gemm1_kernel(
    const float* __restrict__ A,   // NNODE x IND
    const float* __restrict__ W,   // IND x HD
    const float* __restrict__ bias,
    const float* __restrict__ w5,
    float* __restrict__ h_out,     // NNODE x HD
    float* __restrict__ recons) {
    const int m0 = blockIdx.x * 64, n0 = blockIdx.y * 64;
    __shared__ float As[16][64];
    __shared__ float Bs[16][64];
    const int t = threadIdx.x;
    const int tm = t >> 4, tn = t & 15;
    float acc[4][4] = {};
    for (int k0 = 0; k0 < IND; k0 += 16) {
        {   // A tile: 64 rows x 16 k, transposed into As[k][m]
            int m = t >> 2, kq = t & 3;
            int row = m0 + m;
            float4 v = make_float4(0.f, 0.f, 0.f, 0.f);
            if (row < NNODE) v = *(const float4*)(A + (size_t)row * IND + k0 + 4 * kq);
            As[4 * kq + 0][m] = v.x;
            As[4 * kq + 1][m] = v.y;
            As[4 * kq + 2][m] = v.z;
            As[4 * kq + 3][m] = v.w;
        }
        {   // B tile: 16 k x 64 n
            int kk = t >> 4, nq = t & 15;
            float4 v = *(const float4*)(W + (size_t)(k0 + kk) * HD + n0 + 4 * nq);
            *(float4*)&Bs[kk][4 * nq] = v;
        }
        __syncthreads();
#pragma unroll
        for (int kk = 0; kk < 16; ++kk) {
            float4 av = *(const float4*)&As[kk][tm * 4];
            float4 bv = *(const float4*)&Bs[kk][tn * 4];
            float a[4] = {av.x, av.y, av.z, av.w};
            float b[4] = {bv.x, bv.y, bv.z, bv.w};
#pragma unroll
            for (int i = 0; i < 4; ++i)
#pragma unroll
                for (int j = 0; j < 4; ++j)
                    acc[i][j] = fmaf(a[i], b[j], acc[i][j]);
        }
        __syncthreads();
    }
    float w0 = w5[0];
#pragma unroll
    for (int i = 0; i < 4; ++i) {
        int row = m0 + tm * 4 + i;
        if (row >= NNODE) break;
#pragma unroll
        for (int j = 0; j < 4; ++j) {
            int cc = n0 + tn * 4 + j;
            float v = acc[i][j] + bias[cc];
            v = v > 0.0f ? v : 0.01f * v;
            h_out[(size_t)row * HD + cc] = v;
            recons[(size_t)row * HD + cc] = w0 * v;
        }
    }
}

// ---------------------------------------------------------------------------
// 6. Laplacian step (gather form) + recons accumulation
//    out[v][c] = f[v][c] - dinv[v] * sum_{u in nbr(v)} f[u][c]*dinv[u]
// ---------------------------------------------------------------------------
__global__ __launch_bounds__(256) void lap_kernel(
    const float* __restrict__ fin, float* __restrict__ fout,
    float* __restrict__ recons, const float* __restrict__ dinv,
    const int* __restrict__ row_ptr, const int* __restrict__ col,
    const float* __restrict__ w5, int k) {
    const int v = blockIdx.x;
    const int c = threadIdx.x;
    const int beg = row_ptr[v], end = row_ptr[v + 1];
    float s = 0.0f;
    for (int j = beg; j < end; ++j) {
        int u = col[j];
        s = fmaf(fin[(size_t)u * HD + c], dinv[u], s);
    }
    float o = fin[(size_t)v * HD + c] - dinv[v] * s;
    fout[(size_t)v * HD + c] = o;
    recons[(size_t)v * HD + c] += w5[k] * o;
}

// ---------------------------------------------------------------------------
// 7. GEMM2: out = sigmoid(recons @ recons^T), NNODE x NNODE
// ---------------------------------------------------------------------------
__global__ __launch_bounds__(256) void gemm2_kernel(
    const float* __restrict__ R, float* __restrict__ out) {
    const int m0 = blockIdx.x * 64, n0 = blockIdx.y * 64;
    __shared__ float As[16][64];
    __shared__ float Bs[16][64];
    const int t = threadIdx.x;
    const int tm = t >> 4, tn = t & 15;
    float acc[4][4] = {};
    for (int k0 = 0; k0 < HD; k0 += 16) {
        int m = t >> 2, kq = t & 3;
        {
            int row = m0 + m;
            float4 v = make_float4(0.f, 0.f, 0.f, 0.f);
            if (row < NNODE) v = *(const float4*)(R + (size_t)row * HD + k0 + 4 * kq);
            As[4 * kq + 0][m] = v.x;
            As[4 * kq + 1][m] = v.y;
            As[4 * kq + 2][m] = v.z;
            As[4 * kq + 3][m] = v.w;
        }
        {
            int row = n0 + m;
            float4 v = make_float4(0.f, 0.f, 0.f, 0.f);
            if (row < NNODE) v = *(const float4*)(R + (size_t)row * HD + k0 + 4 * kq);
            Bs[4 * kq + 0][m] = v.x;
            Bs[4 * kq + 1][m] = v.y;
            Bs[4 * kq + 2][m] = v.z;
            Bs[4 * kq + 3][m] = v.w;
        }
        __syncthreads();
#pragma unroll
        for (int kk = 0; kk < 16; ++kk) {
            float4 av = *(const float4*)&As[kk][tm * 4];
            float4 bv = *(const float4*)&Bs[kk][tn * 4];
            float a[4] = {av.x, av.y, av.z, av.w};
            float b[4] = {bv.x, bv.y, bv.z, bv.w};
#pragma unroll
            for (int i = 0; i < 4; ++i)
#pragma unroll
                for (int j = 0; j < 4; ++j)
                    acc[i][j] = fmaf(a[i], b[j], acc[i][j]);
        }
        __syncthreads();
    }
#pragma unroll
    for (int i = 0; i < 4; ++i) {
        int row = m0 + tm * 4 + i;
        if (row >= NNODE) break;
#pragma unroll
        for (int j = 0; j < 4; ++j) {
            int cc = n0 + tn * 4 + j;
            if (cc < NNODE) {
                float x = acc[i][j];
                out[(size_t)row * NNODE + cc] = 1.0f / (1.0f + expf(-x));
            }
        }
    }
}

// ---------------------------------------------------------------------------
extern "C" void kernel_launch(void* const* d_in, const int* in_sizes, int n_in,
                              void* d_out, int out_size, void* d_ws, size_t ws_size,
                              hipStream_t stream) {
    const float* in_feat = (const float*)d_in[0];
    const float* W       = (const float*)d_in[1];
    const float* bias    = (const float*)d_in[2];
    const float* lam     = (const float*)d_in[3];
    const int*   src     = (const int*)d_in[4];
    const int*   dst     = (const int*)d_in[5];
    const int    E       = in_sizes[4];   // 330000 (E + N self loops)
    float* out = (float*)d_out;

    // workspace carve-up (256B aligned chunks)
    char* p = (char*)d_ws;
    auto alloc = [&](size_t bytes) -> void* {
        void* r = (void*)p;
        p += (bytes + 255) & ~(size_t)255;
        return r;
    };
    int*   cnts    = (int*)alloc(3 * NNODE * sizeof(int));  // cnt_src | cnt_dst | cursor
    int*   cnt_src = cnts;
    int*   cnt_dst = cnts + NNODE;
    int*   cursor  = cnts + 2 * NNODE;
    int*   row_ptr = (int*)alloc((NNODE + 1) * sizeof(int));
    int*   col     = (int*)alloc((size_t)E * sizeof(int));
    float* dinv    = (float*)alloc(NNODE * sizeof(float));
    float* w5      = (float*)alloc(8 * sizeof(float));
    float* f_a     = (float*)alloc((size_t)NNODE * HD * sizeof(float));
    float* f_b     = (float*)alloc((size_t)NNODE * HD * sizeof(float));
    float* recons  = (float*)alloc((size_t)NNODE * HD * sizeof(float));

    hipMemsetAsync(cnts, 0, 3 * NNODE * sizeof(int), stream);

    int eb = (E + 255) / 256;
    count_kernel<<<eb, 256, 0, stream>>>(src, dst, E, cnt_src, cnt_dst);
    w_kernel<<<1, 64, 0, stream>>>(lam, w5);
    scan_kernel<<<1, 1024, 0, stream>>>(cnt_src, cnt_dst, dinv, row_ptr);
    fill_kernel<<<eb, 256, 0, stream>>>(src, dst, E, row_ptr, cursor, col);

    dim3 g1((NNODE + 63) / 64, HD / 64);
    gemm1_kernel<<<g1, 256, 0, stream>>>(in_feat, W, bias, w5, f_a, recons);

    lap_kernel<<<NNODE, 256, 0, stream>>>(f_a, f_b, recons, dinv, row_ptr, col, w5, 1);
    lap_kernel<<<NNODE, 256, 0, stream>>>(f_b, f_a, recons, dinv, row_ptr, col, w5, 2);
    lap_kernel<<<NNODE, 256, 0, stream>>>(f_a, f_b, recons, dinv, row_ptr, col, w5, 3);
    lap_kernel<<<NNODE, 256, 0, stream>>>(f_b, f_a, recons, dinv, row_ptr, col, w5, 4);

    dim3 g2((NNODE + 63) / 64, (NNODE + 63) / 64);
    gemm2_kernel<<<g2, 256, 0, stream>>>(recons, out);
}

// Round 2
// 710.880 us; speedup vs baseline: 1.6437x; 1.6437x over previous
//
#include <hip/hip_runtime.h>
#include <cstddef>

#define NNODE 10000
#define IND 512
#define HD 256
#define PAD_M 10112   // 79 * 128

typedef __attribute__((ext_vector_type(8))) short short8;
typedef __attribute__((ext_vector_type(4))) float floatx4;

#define GLOAD_LDS16(gp, lp) __builtin_amdgcn_global_load_lds( \
    (const __attribute__((address_space(1))) unsigned int*)(gp), \
    (__attribute__((address_space(3))) unsigned int*)(lp), 16, 0, 0)

// ---------------------------------------------------------------------------
// 1. count degrees (src side for dinv, dst side for CSR rows)
// ---------------------------------------------------------------------------
__global__ void count_kernel(const int* __restrict__ src, const int* __restrict__ dst,
                             int E, int* __restrict__ cnt_src, int* __restrict__ cnt_dst) {
    int e = blockIdx.x * blockDim.x + threadIdx.x;
    if (e < E) {
        atomicAdd(&cnt_src[src[e]], 1);
        atomicAdd(&cnt_dst[dst[e]], 1);
    }
}

// ---------------------------------------------------------------------------
// 2. dinv + exclusive scan of cnt_dst -> row_ptr (single block, 1024 threads)
// ---------------------------------------------------------------------------
__global__ __launch_bounds__(1024) void scan_kernel(const int* __restrict__ cnt_src,
                                                    const int* __restrict__ cnt_dst,
                                                    float* __restrict__ dinv,
                                                    int* __restrict__ row_ptr) {
    int t = threadIdx.x;
    for (int i = t; i < NNODE; i += 1024)
        dinv[i] = rsqrtf(fmaxf((float)cnt_src[i], 1.0f));

    __shared__ int sums[1024];
    const int CH = (NNODE + 1023) / 1024;  // 10
    int base = t * CH;
    int s = 0;
    for (int i = 0; i < CH; ++i) {
        int idx = base + i;
        if (idx < NNODE) s += cnt_dst[idx];
    }
    sums[t] = s;
    __syncthreads();
    for (int off = 1; off < 1024; off <<= 1) {
        int v = (t >= off) ? sums[t - off] : 0;
        __syncthreads();
        sums[t] += v;
        __syncthreads();
    }
    int run = (t == 0) ? 0 : sums[t - 1];
    for (int i = 0; i < CH; ++i) {
        int idx = base + i;
        if (idx < NNODE) { row_ptr[idx] = run; run += cnt_dst[idx]; }
    }
    if (t == 1023) row_ptr[NNODE] = sums[1023];
}

// ---------------------------------------------------------------------------
// 3. fill CSR (by dst): col[] holds src of each edge
// ---------------------------------------------------------------------------
__global__ void fill_kernel(const int* __restrict__ src, const int* __restrict__ dst,
                            int E, const int* __restrict__ row_ptr,
                            int* __restrict__ cursor, int* __restrict__ col) {
    int e = blockIdx.x * blockDim.x + threadIdx.x;
    if (e < E) {
        int v = dst[e];
        int pos = row_ptr[v] + atomicAdd(&cursor[v], 1);
        col[pos] = src[e];
    }
}

// ---------------------------------------------------------------------------
// 4. combine weights w_k = sum_i c_i * THETA[i][k], c = sigmoids of lam
// ---------------------------------------------------------------------------
__global__ void w_kernel(const float* __restrict__ lam, float* __restrict__ w) {
    if (threadIdx.x == 0 && blockIdx.x == 0) {
        float c[5];
        float s0 = 1.0f / (1.0f + expf(-lam[0]));
        c[0] = s0;
        c[1] = s0;  // reference reuses lam[0] for all_h[1]
        c[2] = 1.0f / (1.0f + expf(-lam[1]));
        c[3] = 1.0f / (1.0f + expf(-lam[2]));
        c[4] = 1.0f / (1.0f + expf(-lam[3]));
        const float TH[5][5] = {
            {5.0f, -10.0f,  7.5f, -2.5f, 0.3125f},
            {0.0f,  10.0f, -15.0f, 7.5f, -1.25f },
            {0.0f,   0.0f,  7.5f, -7.5f, 1.875f },
            {0.0f,   0.0f,  0.0f,  2.5f, -1.25f },
            {0.0f,   0.0f,  0.0f,  0.0f, 0.3125f}};
        for (int k = 0; k < 5; ++k) {
            float acc = 0.0f;
            for (int i = 0; i < 5; ++i) acc += c[i] * TH[i][k];
            w[k] = acc;
        }
    }
}

// ---------------------------------------------------------------------------
// 5. GEMM1: h = leaky_relu(in_feat @ W + b); f_a = h; recons = w0 * h
// ---------------------------------------------------------------------------
__global__ __launch_bounds__(256) void gemm1_kernel(
    const float* __restrict__ A,   // NNODE x IND
    const float* __restrict__ W,   // IND x HD
    const float* __restrict__ bias,
    const float* __restrict__ w5,
    float* __restrict__ h_out,     // NNODE x HD
    float* __restrict__ recons) {
    const int m0 = blockIdx.x * 64, n0 = blockIdx.y * 64;
    __shared__ float As[16][64];
    __shared__ float Bs[16][64];
    const int t = threadIdx.x;
    const int tm = t >> 4, tn = t & 15;
    float acc[4][4] = {};
    for (int k0 = 0; k0 < IND; k0 += 16) {
        {
            int m = t >> 2, kq = t & 3;
            int row = m0 + m;
            float4 v = make_float4(0.f, 0.f, 0.f, 0.f);
            if (row < NNODE) v = *(const float4*)(A + (size_t)row * IND + k0 + 4 * kq);
            As[4 * kq + 0][m] = v.x;
            As[4 * kq + 1][m] = v.y;
            As[4 * kq + 2][m] = v.z;
            As[4 * kq + 3][m] = v.w;
        }
        {
            int kk = t >> 4, nq = t & 15;
            float4 v = *(const float4*)(W + (size_t)(k0 + kk) * HD + n0 + 4 * nq);
            *(float4*)&Bs[kk][4 * nq] = v;
        }
        __syncthreads();
#pragma unroll
        for (int kk = 0; kk < 16; ++kk) {
            float4 av = *(const float4*)&As[kk][tm * 4];
            float4 bv = *(const float4*)&Bs[kk][tn * 4];
            float a[4] = {av.x, av.y, av.z, av.w};
            float b[4] = {bv.x, bv.y, bv.z, bv.w};
#pragma unroll
            for (int i = 0; i < 4; ++i)
#pragma unroll
                for (int j = 0; j < 4; ++j)
                    acc[i][j] = fmaf(a[i], b[j], acc[i][j]);
        }
        __syncthreads();
    }
    float w0 = w5[0];
#pragma unroll
    for (int i = 0; i < 4; ++i) {
        int row = m0 + tm * 4 + i;
        if (row >= NNODE) break;
#pragma unroll
        for (int j = 0; j < 4; ++j) {
            int cc = n0 + tn * 4 + j;
            float v = acc[i][j] + bias[cc];
            v = v > 0.0f ? v : 0.01f * v;
            h_out[(size_t)row * HD + cc] = v;
            recons[(size_t)row * HD + cc] = w0 * v;
        }
    }
}

// ---------------------------------------------------------------------------
// 6. Laplacian step (gather form) + recons accumulation
// ---------------------------------------------------------------------------
__global__ __launch_bounds__(256) void lap_kernel(
    const float* __restrict__ fin, float* __restrict__ fout,
    float* __restrict__ recons, const float* __restrict__ dinv,
    const int* __restrict__ row_ptr, const int* __restrict__ col,
    const float* __restrict__ w5, int k) {
    const int v = blockIdx.x;
    const int c = threadIdx.x;
    const int beg = row_ptr[v], end = row_ptr[v + 1];
    float s = 0.0f;
    for (int j = beg; j < end; ++j) {
        int u = col[j];
        s = fmaf(fin[(size_t)u * HD + c], dinv[u], s);
    }
    float o = fin[(size_t)v * HD + c] - dinv[v] * s;
    fout[(size_t)v * HD + c] = o;
    recons[(size_t)v * HD + c] += w5[k] * o;
}

// ---------------------------------------------------------------------------
// 6b. split recons into bf16 hi + lo (truncation; residual <= 2^-16 rel)
// ---------------------------------------------------------------------------
__global__ void split_kernel(const float* __restrict__ R,
                             unsigned short* __restrict__ Rhi,
                             unsigned short* __restrict__ Rlo) {
    int i = blockIdx.x * blockDim.x + threadIdx.x;
    if (i < NNODE * HD) {
        float r = R[i];
        unsigned u = __float_as_uint(r);
        float hif = __uint_as_float(u & 0xFFFF0000u);
        float lof = r - hif;   // exact (same binade)
        Rhi[i] = (unsigned short)(u >> 16);
        Rlo[i] = (unsigned short)(__float_as_uint(lof) >> 16);
    }
}

// ---------------------------------------------------------------------------
// 7. GEMM2 (MFMA): out = sigmoid(R R^T) via Hi Hi^T + Hi Lo^T + Lo Hi^T
//    128x128 tile, 4 waves (2x2), 64x64 per wave, BK=64, m97-style 2-barrier
// ---------------------------------------------------------------------------
__global__ __launch_bounds__(256) void gemm2_mfma(
    const unsigned short* __restrict__ Rhi,
    const unsigned short* __restrict__ Rlo,
    float* __restrict__ out) {
    __shared__ unsigned short As[128][64];
    __shared__ unsigned short Bs[128][64];
    const int t = threadIdx.x;
    const int lane = t & 63;
    const int wave = t >> 6;
    const int wm = wave >> 1, wn = wave & 1;
    const int brow = blockIdx.x * 128, bcol = blockIdx.y * 128;
    const int fr = lane & 15;   // fragment row (A) / col (B)
    const int kq = lane >> 4;   // k-quarter

    floatx4 acc[4][4];
#pragma unroll
    for (int i = 0; i < 4; ++i)
#pragma unroll
        for (int j = 0; j < 4; ++j)
            acc[i][j] = (floatx4){0.f, 0.f, 0.f, 0.f};

    const int srow = t >> 3;           // 0..31
    const int scol = (t & 7) * 8;      // 0..56

    for (int ks = 0; ks < 12; ++ks) {
        const int seg = ks >> 2;
        const int k0 = (ks & 3) * 64;
        const unsigned short* Aseg = (seg < 2) ? Rhi : Rlo;
        const unsigned short* Bseg = (seg == 1) ? Rlo : Rhi;
#pragma unroll
        for (int q = 0; q < 4; ++q) {
            const unsigned short* ga = Aseg + (size_t)(brow + q * 32 + srow) * HD + k0 + scol;
            const unsigned short* gb = Bseg + (size_t)(bcol + q * 32 + srow) * HD + k0 + scol;
            GLOAD_LDS16(ga, &As[0][0] + q * 2048 + t * 8);
            GLOAD_LDS16(gb, &Bs[0][0] + q * 2048 + t * 8);
        }
        __syncthreads();   // drains vmcnt before reads
#pragma unroll
        for (int kk = 0; kk < 2; ++kk) {
            short8 a[4], b[4];
#pragma unroll
            for (int i = 0; i < 4; ++i)
                a[i] = *(const short8*)&As[wm * 64 + i * 16 + fr][kk * 32 + kq * 8];
#pragma unroll
            for (int j = 0; j < 4; ++j)
                b[j] = *(const short8*)&Bs[wn * 64 + j * 16 + fr][kk * 32 + kq * 8];
#pragma unroll
            for (int i = 0; i < 4; ++i)
#pragma unroll
                for (int j = 0; j < 4; ++j)
                    acc[i][j] = __builtin_amdgcn_mfma_f32_16x16x32_bf16(
                        a[i], b[j], acc[i][j], 0, 0, 0);
        }
        __syncthreads();   // tile consumed; safe to overwrite
    }

    // epilogue: C/D layout col=lane&15, row=(lane>>4)*4+reg
    const int orow0 = brow + wm * 64 + (lane >> 4) * 4;
    const int ocol0 = bcol + wn * 64 + fr;
#pragma unroll
    for (int i = 0; i < 4; ++i) {
#pragma unroll
        for (int j = 0; j < 4; ++j) {
            int col = ocol0 + j * 16;
#pragma unroll
            for (int r = 0; r < 4; ++r) {
                int row = orow0 + i * 16 + r;
                if (row < NNODE && col < NNODE) {
                    float x = acc[i][j][r];
                    out[(size_t)row * NNODE + col] = 1.0f / (1.0f + __expf(-x));
                }
            }
        }
    }
}

// ---------------------------------------------------------------------------
extern "C" void kernel_launch(void* const* d_in, const int* in_sizes, int n_in,
                              void* d_out, int out_size, void* d_ws, size_t ws_size,
                              hipStream_t stream) {
    const float* in_feat = (const float*)d_in[0];
    const float* W       = (const float*)d_in[1];
    const float* bias    = (const float*)d_in[2];
    const float* lam     = (const float*)d_in[3];
    const int*   src     = (const int*)d_in[4];
    const int*   dst     = (const int*)d_in[5];
    const int    E       = in_sizes[4];
    float* out = (float*)d_out;

    char* p = (char*)d_ws;
    auto alloc = [&](size_t bytes) -> void* {
        void* r = (void*)p;
        p += (bytes + 255) & ~(size_t)255;
        return r;
    };
    int*   cnts    = (int*)alloc(3 * NNODE * sizeof(int));
    int*   cnt_src = cnts;
    int*   cnt_dst = cnts + NNODE;
    int*   cursor  = cnts + 2 * NNODE;
    int*   row_ptr = (int*)alloc((NNODE + 1) * sizeof(int));
    int*   col     = (int*)alloc((size_t)E * sizeof(int));
    float* dinv    = (float*)alloc(NNODE * sizeof(float));
    float* w5      = (float*)alloc(8 * sizeof(float));
    float* f_a     = (float*)alloc((size_t)NNODE * HD * sizeof(float));
    float* f_b     = (float*)alloc((size_t)NNODE * HD * sizeof(float));
    float* recons  = (float*)alloc((size_t)NNODE * HD * sizeof(float));
    unsigned short* Rhi = (unsigned short*)alloc((size_t)PAD_M * HD * sizeof(unsigned short));
    unsigned short* Rlo = (unsigned short*)alloc((size_t)PAD_M * HD * sizeof(unsigned short));

    hipMemsetAsync(cnts, 0, 3 * NNODE * sizeof(int), stream);
    // zero pad rows of the bf16 panels (discarded outputs, but keep them finite)
    hipMemsetAsync(Rhi + (size_t)NNODE * HD, 0, (size_t)(PAD_M - NNODE) * HD * 2, stream);
    hipMemsetAsync(Rlo + (size_t)NNODE * HD, 0, (size_t)(PAD_M - NNODE) * HD * 2, stream);

    int eb = (E + 255) / 256;
    count_kernel<<<eb, 256, 0, stream>>>(src, dst, E, cnt_src, cnt_dst);
    w_kernel<<<1, 64, 0, stream>>>(lam, w5);
    scan_kernel<<<1, 1024, 0, stream>>>(cnt_src, cnt_dst, dinv, row_ptr);
    fill_kernel<<<eb, 256, 0, stream>>>(src, dst, E, row_ptr, cursor, col);

    dim3 g1((NNODE + 63) / 64, HD / 64);
    gemm1_kernel<<<g1, 256, 0, stream>>>(in_feat, W, bias, w5, f_a, recons);

    lap_kernel<<<NNODE, 256, 0, stream>>>(f_a, f_b, recons, dinv, row_ptr, col, w5, 1);
    lap_kernel<<<NNODE, 256, 0, stream>>>(f_b, f_a, recons, dinv, row_ptr, col, w5, 2);
    lap_kernel<<<NNODE, 256, 0, stream>>>(f_a, f_b, recons, dinv, row_ptr, col, w5, 3);
    lap_kernel<<<NNODE, 256, 0, stream>>>(f_b, f_a, recons, dinv, row_ptr, col, w5, 4);

    split_kernel<<<(NNODE * HD + 255) / 256, 256, 0, stream>>>(recons, Rhi, Rlo);

    dim3 g2(PAD_M / 128, PAD_M / 128);
    gemm2_mfma<<<g2, 256, 0, stream>>>(Rhi, Rlo, out);
}